// Round 1
// baseline (234.920 us; speedup 1.0000x reference)
//
#include <hip/hip_runtime.h>
#include <hip/hip_bf16.h>
#include <stdint.h>

typedef __attribute__((ext_vector_type(8))) short short8;
typedef __attribute__((ext_vector_type(4))) float f32x4;

static __device__ __forceinline__ unsigned short f2bf(float f) {
  union { float f; unsigned u; } v; v.f = f;
  return (unsigned short)((v.u + 0x7fffu + ((v.u >> 16) & 1u)) >> 16);
}
static __device__ __forceinline__ float bf2f(unsigned short h) {
  union { unsigned u; float f; } v; v.u = ((unsigned)h) << 16;
  return v.f;
}

// async global->LDS, 16B per lane (guide §5; LDS dest = wave-uniform base + lane*16)
#define GLL16(gp, lp) __builtin_amdgcn_global_load_lds(                        \
    (__attribute__((address_space(1))) void*)(uintptr_t)(gp),                  \
    (__attribute__((address_space(3))) void*)(lp), 16, 0, 0)

// ---------------- cast f32 -> bf16, 4 elems/thread ----------------
__global__ void cast_f32_bf16(const float* __restrict__ in,
                              unsigned short* __restrict__ out, int n4) {
  int i = blockIdx.x * 256 + threadIdx.x;
  if (i >= n4) return;
  const float4 v = reinterpret_cast<const float4*>(in)[i];
  ushort4 o;
  o.x = f2bf(v.x); o.y = f2bf(v.y); o.z = f2bf(v.z); o.w = f2bf(v.w);
  reinterpret_cast<ushort4*>(out)[i] = o;
}

// ---------------- NT GEMM: C[M][N] = A[M][K] * B[N][K]^T (bf16 in, f32 acc) --
// 128x128 tile, BK=32, 256 threads (2x2 waves, each 64x64 = 4x4 16x16 frags)
template <int OUT_BF16>
__global__ __launch_bounds__(256) void gemm_nt(
    const unsigned short* __restrict__ A, const unsigned short* __restrict__ B,
    void* __restrict__ Cout, int M, int N, int K) {
  __shared__ unsigned short As[128 * 32];
  __shared__ unsigned short Bs[128 * 32];
  const int tid = threadIdx.x;
  const int lane = tid & 63;
  const int w = tid >> 6;
  const int wr = w >> 1, wc = w & 1;
  const int l15 = lane & 15, lg = lane >> 4;
  const size_t bm = (size_t)blockIdx.x * 128;
  const size_t bn = (size_t)blockIdx.y * 128;
  const unsigned short* Ab = A + bm * K;
  const unsigned short* Bb = B + bn * K;
  f32x4 acc[4][4];
#pragma unroll
  for (int m = 0; m < 4; ++m)
#pragma unroll
    for (int n = 0; n < 4; ++n) acc[m][n] = (f32x4){0.f, 0.f, 0.f, 0.f};

  for (int k0 = 0; k0 < K; k0 += 32) {
    __syncthreads();
#pragma unroll
    for (int p = 0; p < 2; ++p) {
      const int flat = p * 256 + tid;     // 0..511
      const int row = flat >> 2;          // 128 rows, 4 chunks/row
      const int c8 = (flat & 3) << 3;
      GLL16(Ab + (size_t)row * K + k0 + c8, As + flat * 8);
      GLL16(Bb + (size_t)row * K + k0 + c8, Bs + flat * 8);
    }
    __syncthreads();
    short8 af[4], bf[4];
#pragma unroll
    for (int m = 0; m < 4; ++m)
      af[m] = *reinterpret_cast<const short8*>(As + ((wr * 64 + m * 16 + l15) * 32 + lg * 8));
#pragma unroll
    for (int n = 0; n < 4; ++n)
      bf[n] = *reinterpret_cast<const short8*>(Bs + ((wc * 64 + n * 16 + l15) * 32 + lg * 8));
#pragma unroll
    for (int m = 0; m < 4; ++m)
#pragma unroll
      for (int n = 0; n < 4; ++n)
        acc[m][n] = __builtin_amdgcn_mfma_f32_16x16x32_bf16(af[m], bf[n], acc[m][n], 0, 0, 0);
  }
  const size_t row0 = bm + wr * 64 + lg * 4;
  const size_t col0 = bn + wc * 64 + l15;
#pragma unroll
  for (int m = 0; m < 4; ++m)
#pragma unroll
    for (int n = 0; n < 4; ++n)
#pragma unroll
      for (int r = 0; r < 4; ++r) {
        const size_t row = row0 + m * 16 + r;
        const size_t col = col0 + n * 16;
        if (OUT_BF16)
          ((unsigned short*)Cout)[row * N + col] = f2bf(acc[m][n][r]);
        else
          ((float*)Cout)[row * N + col] = acc[m][n][r];
      }
}

// ---------------- RoPE on q,k; angles = h * 10000^(-jj/32) ------------------
// qkv rows m=b*2048+t, cols: [0,1024)=q [1024,2048)=k. Writes (b,h,t,d) bf16.
__global__ void rope_qk(const unsigned short* __restrict__ qkvb,
                        unsigned short* __restrict__ qb,
                        unsigned short* __restrict__ kb) {
  const int idx = blockIdx.x * 256 + threadIdx.x;  // 4096*1024 total
  const int m = idx >> 10;
  const int r = idx & 1023;
  const int sec = r >> 9;  // 0=q, 1=k
  const int j = r & 511;
  const int h = j >> 5;
  const int jj = j & 31;
  const float freq = __expf(-(float)jj * (9.210340371976184f / 32.0f));  // ln(1e4)
  float s, c;
  __sincosf((float)h * freq, &s, &c);
  const unsigned pr = *reinterpret_cast<const unsigned*>(
      qkvb + (size_t)m * 3072 + sec * 1024 + h * 64 + 2 * jj);
  const float x0 = bf2f((unsigned short)(pr & 0xffffu));
  const float x1 = bf2f((unsigned short)(pr >> 16));
  const float o0 = x0 * c - x1 * s;
  const float o1 = x0 * s + x1 * c;
  const unsigned out = (unsigned)f2bf(o0) | ((unsigned)f2bf(o1) << 16);
  const int b = m >> 11, t = m & 2047;
  unsigned short* dst = (sec == 0) ? qb : kb;
  *reinterpret_cast<unsigned*>(dst + (((size_t)(b * 16 + h) * 2048 + t) * 64 + 2 * jj)) = out;
}

// ---------------- V transpose: qkv v-section -> vt[(b,h,d,s)] bf16 ----------
__global__ void v_transpose(const unsigned short* __restrict__ qkvb,
                            unsigned short* __restrict__ vt) {
  __shared__ unsigned short tile[64][66];  // +2 pad: conflict-free column reads
  const int tid = threadIdx.x;
  const int bh = blockIdx.x;
  const int b = bh >> 4, h = bh & 15;
  const int s0 = blockIdx.y * 64;
#pragma unroll
  for (int p = 0; p < 2; ++p) {
    const int f = p * 256 + tid;
    const int sr = f >> 3;
    const int c8 = (f & 7) << 3;
    const short8 v = *reinterpret_cast<const short8*>(
        qkvb + (size_t)(b * 2048 + s0 + sr) * 3072 + 2048 + h * 64 + c8);
#pragma unroll
    for (int e = 0; e < 8; ++e) tile[sr][c8 + e] = (unsigned short)v[e];
  }
  __syncthreads();
#pragma unroll
  for (int p = 0; p < 2; ++p) {
    const int f = p * 256 + tid;
    const int dr = f >> 3;
    const int s8 = (f & 7) << 3;
    short8 o;
#pragma unroll
    for (int e = 0; e < 8; ++e) o[e] = (short)tile[s8 + e][dr];
    *reinterpret_cast<short8*>(vt + ((size_t)bh * 64 + dr) * 2048 + s0 + s8) = o;
  }
}

// ---------------- flash attention, causal, per-wave online softmax ----------
// grid (T/64, B*H), 256 thr. Wave w owns q-rows [q0+16w, q0+16w+15].
__global__ __launch_bounds__(256) void attn_kernel(
    const unsigned short* __restrict__ qb, const unsigned short* __restrict__ kb,
    const unsigned short* __restrict__ vt, unsigned short* __restrict__ ctx) {
  __shared__ unsigned short Ks[64 * 64];     // [s][d]
  __shared__ unsigned short Vs[64 * 64];     // [d][s] (pre-transposed in global)
  __shared__ unsigned short Ps[4][16 * 64];  // per-wave P tile [q][s]
  const int tid = threadIdx.x;
  const int lane = tid & 63;
  const int w = tid >> 6;
  const int l15 = lane & 15, lg = lane >> 4;
  const int bh = blockIdx.y;
  const int q0 = blockIdx.x * 64;
  const int qw = q0 + w * 16;
  const unsigned short* Qp = qb + ((size_t)bh * 2048 + qw) * 64;
  const short8 qf0 = *reinterpret_cast<const short8*>(Qp + (size_t)l15 * 64 + lg * 8);
  const short8 qf1 = *reinterpret_cast<const short8*>(Qp + (size_t)l15 * 64 + 32 + lg * 8);
  float mrun[4], lrun[4];
  f32x4 o[4];
#pragma unroll
  for (int r = 0; r < 4; ++r) { mrun[r] = -1e30f; lrun[r] = 0.f; }
#pragma unroll
  for (int dt = 0; dt < 4; ++dt) o[dt] = (f32x4){0.f, 0.f, 0.f, 0.f};
  const int ntile = blockIdx.x + 1;
  for (int it = 0; it < ntile; ++it) {
    const int s0 = it * 64;
    __syncthreads();
#pragma unroll
    for (int p = 0; p < 2; ++p) {
      const int f = p * 256 + tid;
      const int row = f >> 3;
      const int c8 = (f & 7) << 3;
      GLL16(kb + ((size_t)bh * 2048 + s0 + row) * 64 + c8, Ks + f * 8);
      GLL16(vt + ((size_t)bh * 64 + row) * 2048 + s0 + c8, Vs + f * 8);
    }
    __syncthreads();
    // QK^T: S[16q][64s]
    f32x4 sc[4];
#pragma unroll
    for (int st = 0; st < 4; ++st) {
      const short8 kf0 = *reinterpret_cast<const short8*>(Ks + (st * 16 + l15) * 64 + lg * 8);
      const short8 kf1 = *reinterpret_cast<const short8*>(Ks + (st * 16 + l15) * 64 + 32 + lg * 8);
      f32x4 z = (f32x4){0.f, 0.f, 0.f, 0.f};
      z = __builtin_amdgcn_mfma_f32_16x16x32_bf16(qf0, kf0, z, 0, 0, 0);
      z = __builtin_amdgcn_mfma_f32_16x16x32_bf16(qf1, kf1, z, 0, 0, 0);
      sc[st] = z;
    }
    // scale + causal mask + row max (rows live across 16 lanes, 4 regs)
    float tmax[4] = {-1e30f, -1e30f, -1e30f, -1e30f};
#pragma unroll
    for (int st = 0; st < 4; ++st)
#pragma unroll
      for (int r = 0; r < 4; ++r) {
        float v = sc[st][r] * 0.125f;
        if (s0 + st * 16 + l15 > qw + lg * 4 + r) v = -1e30f;
        sc[st][r] = v;
        tmax[r] = fmaxf(tmax[r], v);
      }
#pragma unroll
    for (int r = 0; r < 4; ++r) {
      tmax[r] = fmaxf(tmax[r], __shfl_xor(tmax[r], 1));
      tmax[r] = fmaxf(tmax[r], __shfl_xor(tmax[r], 2));
      tmax[r] = fmaxf(tmax[r], __shfl_xor(tmax[r], 4));
      tmax[r] = fmaxf(tmax[r], __shfl_xor(tmax[r], 8));
    }
    float corr[4], psum[4];
#pragma unroll
    for (int r = 0; r < 4; ++r) {
      const float mn = fmaxf(mrun[r], tmax[r]);
      corr[r] = __expf(mrun[r] - mn);
      mrun[r] = mn;
      psum[r] = 0.f;
    }
    unsigned short* Pw = &Ps[w][0];
#pragma unroll
    for (int st = 0; st < 4; ++st)
#pragma unroll
      for (int r = 0; r < 4; ++r) {
        const float p = __expf(sc[st][r] - mrun[r]);
        psum[r] += p;
        Pw[(lg * 4 + r) * 64 + st * 16 + l15] = f2bf(p);  // C-frag -> [q][s] in LDS
      }
#pragma unroll
    for (int r = 0; r < 4; ++r) {
      psum[r] += __shfl_xor(psum[r], 1);
      psum[r] += __shfl_xor(psum[r], 2);
      psum[r] += __shfl_xor(psum[r], 4);
      psum[r] += __shfl_xor(psum[r], 8);
      lrun[r] = lrun[r] * corr[r] + psum[r];
    }
#pragma unroll
    for (int dt = 0; dt < 4; ++dt)
#pragma unroll
      for (int r = 0; r < 4; ++r) o[dt][r] *= corr[r];
    // PV: O[16q][64d] += P[16q][64s] * V[64s][64d]
#pragma unroll
    for (int sc2 = 0; sc2 < 2; ++sc2) {
      const short8 pf = *reinterpret_cast<const short8*>(Pw + l15 * 64 + sc2 * 32 + lg * 8);
#pragma unroll
      for (int dt = 0; dt < 4; ++dt) {
        const short8 vf =
            *reinterpret_cast<const short8*>(Vs + (dt * 16 + l15) * 64 + sc2 * 32 + lg * 8);
        o[dt] = __builtin_amdgcn_mfma_f32_16x16x32_bf16(pf, vf, o[dt], 0, 0, 0);
      }
    }
  }
  const int b = bh >> 4, h = bh & 15;
#pragma unroll
  for (int dt = 0; dt < 4; ++dt)
#pragma unroll
    for (int r = 0; r < 4; ++r) {
      const int t = qw + lg * 4 + r;
      const float val = o[dt][r] / lrun[r];
      ctx[(size_t)(b * 2048 + t) * 1024 + h * 64 + dt * 16 + l15] = f2bf(val);
    }
}

// ---------------- launch ----------------------------------------------------
extern "C" void kernel_launch(void* const* d_in, const int* in_sizes, int n_in,
                              void* d_out, int out_size, void* d_ws, size_t ws_size,
                              hipStream_t stream) {
  const float* x = (const float*)d_in[0];
  const float* w_qkv = (const float*)d_in[1];
  const float* w_out = (const float*)d_in[2];
  // cache_k/cache_v/start_pos unused: start_pos=0, cache starts zero and is not returned.
  char* ws = (char*)d_ws;
  unsigned short* xb    = (unsigned short*)(ws);                       // 8 MiB
  unsigned short* wqkvb = (unsigned short*)(ws + (8ull  << 20));       // 6 MiB
  unsigned short* woutb = (unsigned short*)(ws + (14ull << 20));       // 2 MiB
  unsigned short* qkvb  = (unsigned short*)(ws + (16ull << 20));       // 24 MiB
  unsigned short* q_buf = (unsigned short*)(ws + (40ull << 20));       // 8 MiB
  unsigned short* k_buf = (unsigned short*)(ws + (48ull << 20));       // 8 MiB
  unsigned short* vt    = (unsigned short*)(ws + (56ull << 20));       // 8 MiB
  unsigned short* ctxb  = (unsigned short*)(ws + (64ull << 20));       // 8 MiB (total 72)

  cast_f32_bf16<<<4096, 256, 0, stream>>>(x, xb, 4194304 / 4);
  cast_f32_bf16<<<3072, 256, 0, stream>>>(w_qkv, wqkvb, 3145728 / 4);
  cast_f32_bf16<<<1024, 256, 0, stream>>>(w_out, woutb, 1048576 / 4);
  gemm_nt<1><<<dim3(32, 24), 256, 0, stream>>>(xb, wqkvb, qkvb, 4096, 3072, 1024);
  rope_qk<<<16384, 256, 0, stream>>>(qkvb, q_buf, k_buf);
  v_transpose<<<dim3(32, 32), 256, 0, stream>>>(qkvb, vt);
  attn_kernel<<<dim3(32, 32), 256, 0, stream>>>(q_buf, k_buf, vt, ctxb);
  gemm_nt<0><<<dim3(32, 8), 256, 0, stream>>>(ctxb, woutb, d_out, 4096, 1024, 1024);
}

// Round 2
// 166.326 us; speedup vs baseline: 1.4124x; 1.4124x over previous
//
#include <hip/hip_runtime.h>
#include <hip/hip_bf16.h>
#include <stdint.h>

typedef __attribute__((ext_vector_type(8))) short short8;
typedef __attribute__((ext_vector_type(4))) float f32x4;

static __device__ __forceinline__ unsigned short f2bf(float f) {
  union { float f; unsigned u; } v; v.f = f;
  return (unsigned short)((v.u + 0x7fffu + ((v.u >> 16) & 1u)) >> 16);
}
static __device__ __forceinline__ float bf2f(unsigned short h) {
  union { unsigned u; float f; } v; v.u = ((unsigned)h) << 16;
  return v.f;
}

// async global->LDS, 16B per lane (guide §5; LDS dest = wave-uniform base + lane*16)
#define GLL16(gp, lp) __builtin_amdgcn_global_load_lds(                        \
    (__attribute__((address_space(1))) void*)(uintptr_t)(gp),                  \
    (__attribute__((address_space(3))) void*)(lp), 16, 0, 0)

// element-index XOR swizzle for 64-elem (128B) bf16 rows: spreads the
// 128B-stride column reads across 8 bank-granules (T2; involution).
#define SWZ(r, e) ((e) ^ (((r) & 7) << 3))

// ---------------- cast f32 -> bf16, 4 elems/thread ----------------
__global__ void cast_f32_bf16(const float* __restrict__ in,
                              unsigned short* __restrict__ out, int n4) {
  int i = blockIdx.x * 256 + threadIdx.x;
  if (i >= n4) return;
  const float4 v = reinterpret_cast<const float4*>(in)[i];
  ushort4 o;
  o.x = f2bf(v.x); o.y = f2bf(v.y); o.z = f2bf(v.z); o.w = f2bf(v.w);
  reinterpret_cast<ushort4*>(out)[i] = o;
}

// ---------------- NT GEMM: C[M][N] = A[M][K] * B[N][K]^T (bf16 in, f32 acc) --
// 128x128 tile, BK=32, 256 threads (2x2 waves, each 64x64 = 4x4 16x16 frags)
template <int OUT_BF16>
__global__ __launch_bounds__(256) void gemm_nt(
    const unsigned short* __restrict__ A, const unsigned short* __restrict__ B,
    void* __restrict__ Cout, int M, int N, int K) {
  __shared__ unsigned short As[128 * 32];
  __shared__ unsigned short Bs[128 * 32];
  const int tid = threadIdx.x;
  const int lane = tid & 63;
  const int w = tid >> 6;
  const int wr = w >> 1, wc = w & 1;
  const int l15 = lane & 15, lg = lane >> 4;
  const size_t bm = (size_t)blockIdx.x * 128;
  const size_t bn = (size_t)blockIdx.y * 128;
  const unsigned short* Ab = A + bm * K;
  const unsigned short* Bb = B + bn * K;
  f32x4 acc[4][4];
#pragma unroll
  for (int m = 0; m < 4; ++m)
#pragma unroll
    for (int n = 0; n < 4; ++n) acc[m][n] = (f32x4){0.f, 0.f, 0.f, 0.f};

  for (int k0 = 0; k0 < K; k0 += 32) {
    __syncthreads();
#pragma unroll
    for (int p = 0; p < 2; ++p) {
      const int flat = p * 256 + tid;     // 0..511
      const int row = flat >> 2;          // 128 rows, 4 chunks/row
      const int c8 = (flat & 3) << 3;
      GLL16(Ab + (size_t)row * K + k0 + c8, As + flat * 8);
      GLL16(Bb + (size_t)row * K + k0 + c8, Bs + flat * 8);
    }
    __syncthreads();
    short8 af[4], bf[4];
#pragma unroll
    for (int m = 0; m < 4; ++m)
      af[m] = *reinterpret_cast<const short8*>(As + ((wr * 64 + m * 16 + l15) * 32 + lg * 8));
#pragma unroll
    for (int n = 0; n < 4; ++n)
      bf[n] = *reinterpret_cast<const short8*>(Bs + ((wc * 64 + n * 16 + l15) * 32 + lg * 8));
#pragma unroll
    for (int m = 0; m < 4; ++m)
#pragma unroll
      for (int n = 0; n < 4; ++n)
        acc[m][n] = __builtin_amdgcn_mfma_f32_16x16x32_bf16(af[m], bf[n], acc[m][n], 0, 0, 0);
  }
  const size_t row0 = bm + wr * 64 + lg * 4;
  const size_t col0 = bn + wc * 64 + l15;
#pragma unroll
  for (int m = 0; m < 4; ++m)
#pragma unroll
    for (int n = 0; n < 4; ++n)
#pragma unroll
      for (int r = 0; r < 4; ++r) {
        const size_t row = row0 + m * 16 + r;
        const size_t col = col0 + n * 16;
        if (OUT_BF16)
          ((unsigned short*)Cout)[row * N + col] = f2bf(acc[m][n][r]);
        else
          ((float*)Cout)[row * N + col] = acc[m][n][r];
      }
}

// ---------------- RoPE on q,k; angles = h * 10000^(-jj/32) ------------------
// qkv rows m=b*2048+t, cols: [0,1024)=q [1024,2048)=k. Writes (b,h,t,d) bf16.
__global__ void rope_qk(const unsigned short* __restrict__ qkvb,
                        unsigned short* __restrict__ qb,
                        unsigned short* __restrict__ kb) {
  const int idx = blockIdx.x * 256 + threadIdx.x;  // 4096*1024 total
  const int m = idx >> 10;
  const int r = idx & 1023;
  const int sec = r >> 9;  // 0=q, 1=k
  const int j = r & 511;
  const int h = j >> 5;
  const int jj = j & 31;
  const float freq = __expf(-(float)jj * (9.210340371976184f / 32.0f));  // ln(1e4)
  float s, c;
  __sincosf((float)h * freq, &s, &c);
  const unsigned pr = *reinterpret_cast<const unsigned*>(
      qkvb + (size_t)m * 3072 + sec * 1024 + h * 64 + 2 * jj);
  const float x0 = bf2f((unsigned short)(pr & 0xffffu));
  const float x1 = bf2f((unsigned short)(pr >> 16));
  const float o0 = x0 * c - x1 * s;
  const float o1 = x0 * s + x1 * c;
  const unsigned out = (unsigned)f2bf(o0) | ((unsigned)f2bf(o1) << 16);
  const int b = m >> 11, t = m & 2047;
  unsigned short* dst = (sec == 0) ? qb : kb;
  *reinterpret_cast<unsigned*>(dst + (((size_t)(b * 16 + h) * 2048 + t) * 64 + 2 * jj)) = out;
}

// ---------------- V transpose: qkv v-section -> vt[(b,h,d,s)] bf16 ----------
__global__ void v_transpose(const unsigned short* __restrict__ qkvb,
                            unsigned short* __restrict__ vt) {
  __shared__ unsigned short tile[64][66];  // +2 pad: conflict-free column reads
  const int tid = threadIdx.x;
  const int bh = blockIdx.x;
  const int b = bh >> 4, h = bh & 15;
  const int s0 = blockIdx.y * 64;
#pragma unroll
  for (int p = 0; p < 2; ++p) {
    const int f = p * 256 + tid;
    const int sr = f >> 3;
    const int c8 = (f & 7) << 3;
    const short8 v = *reinterpret_cast<const short8*>(
        qkvb + (size_t)(b * 2048 + s0 + sr) * 3072 + 2048 + h * 64 + c8);
#pragma unroll
    for (int e = 0; e < 8; ++e) tile[sr][c8 + e] = (unsigned short)v[e];
  }
  __syncthreads();
#pragma unroll
  for (int p = 0; p < 2; ++p) {
    const int f = p * 256 + tid;
    const int dr = f >> 3;
    const int s8 = (f & 7) << 3;
    short8 o;
#pragma unroll
    for (int e = 0; e < 8; ++e) o[e] = (short)tile[s8 + e][dr];
    *reinterpret_cast<short8*>(vt + ((size_t)bh * 64 + dr) * 2048 + s0 + s8) = o;
  }
}

// ---------------- flash attention, causal, per-wave online softmax ----------
// grid (16, B*H). Block pairs q-tiles (x, 31-x): uniform 33 s-tiles/block.
// K/V double-buffered + prefetch-before-compute (T3-minimal, 1 barrier/tile).
// K/V/P LDS tiles XOR-swizzled (T2) - conflict-free ds_read_b128.
__global__ __launch_bounds__(256) void attn_kernel(
    const unsigned short* __restrict__ qb, const unsigned short* __restrict__ kb,
    const unsigned short* __restrict__ vt, unsigned short* __restrict__ ctx) {
  __shared__ unsigned short Ks[2][64 * 64];  // [s][d], swizzled
  __shared__ unsigned short Vs[2][64 * 64];  // [d][s], swizzled
  __shared__ unsigned short Ps[4][16 * 64];  // per-wave P [q][s], swizzled
  const int tid = threadIdx.x;
  const int lane = tid & 63;
  const int w = tid >> 6;
  const int l15 = lane & 15, lg = lane >> 4;
  const int bh = blockIdx.y;
  const int b = bh >> 4, h = bh & 15;
  unsigned short* Pw = &Ps[w][0];
  const float SCL = 0.125f * 1.44269504089f;  // 1/sqrt(64) * log2(e)

#pragma unroll 1
  for (int mem = 0; mem < 2; ++mem) {
    const int qt = mem ? (31 - (int)blockIdx.x) : (int)blockIdx.x;
    const int qw = qt * 64 + w * 16;
    const unsigned short* Qp = qb + ((size_t)bh * 2048 + qw) * 64;
    const short8 qf0 = *reinterpret_cast<const short8*>(Qp + (size_t)l15 * 64 + lg * 8);
    const short8 qf1 = *reinterpret_cast<const short8*>(Qp + (size_t)l15 * 64 + 32 + lg * 8);
    float mrun[4], lrun[4];
    f32x4 o[4];
#pragma unroll
    for (int r = 0; r < 4; ++r) { mrun[r] = -1e30f; lrun[r] = 0.f; }
#pragma unroll
    for (int dt = 0; dt < 4; ++dt) o[dt] = (f32x4){0.f, 0.f, 0.f, 0.f};
    const int nt = qt + 1;

    // prologue stage into buf 0 (pre-swizzled global source, rule #21)
#pragma unroll
    for (int p = 0; p < 2; ++p) {
      const int f = p * 256 + tid;
      const int row = f >> 3;
      const int gc8 = SWZ(row, (f & 7) << 3);
      GLL16(kb + ((size_t)bh * 2048 + row) * 64 + gc8, &Ks[0][f * 8]);
      GLL16(vt + ((size_t)bh * 64 + row) * 2048 + gc8, &Vs[0][f * 8]);
    }
    __syncthreads();

    int cur = 0;
#pragma unroll 1
    for (int it = 0; it < nt; ++it) {
      const int s0 = it * 64;
      // issue next tile's loads BEFORE compute - latency hides under compute
      if (it + 1 < nt) {
        const int s1 = s0 + 64;
#pragma unroll
        for (int p = 0; p < 2; ++p) {
          const int f = p * 256 + tid;
          const int row = f >> 3;
          const int gc8 = SWZ(row, (f & 7) << 3);
          GLL16(kb + ((size_t)bh * 2048 + s1 + row) * 64 + gc8, &Ks[cur ^ 1][f * 8]);
          GLL16(vt + ((size_t)bh * 64 + row) * 2048 + s1 + gc8, &Vs[cur ^ 1][f * 8]);
        }
      }
      const unsigned short* Kc = &Ks[cur][0];
      const unsigned short* Vc = &Vs[cur][0];
      // QK^T: S[16q][64s]
      f32x4 sc[4];
#pragma unroll
      for (int st = 0; st < 4; ++st) {
        const int kr = st * 16 + l15;
        const short8 kf0 = *reinterpret_cast<const short8*>(Kc + kr * 64 + SWZ(kr, lg * 8));
        const short8 kf1 = *reinterpret_cast<const short8*>(Kc + kr * 64 + SWZ(kr, 32 + lg * 8));
        f32x4 z = (f32x4){0.f, 0.f, 0.f, 0.f};
        z = __builtin_amdgcn_mfma_f32_16x16x32_bf16(qf0, kf0, z, 0, 0, 0);
        z = __builtin_amdgcn_mfma_f32_16x16x32_bf16(qf1, kf1, z, 0, 0, 0);
        sc[st] = z;
      }
      // scale (log2 domain) + causal mask + row max
      float tmax[4] = {-1e30f, -1e30f, -1e30f, -1e30f};
      if (s0 + 63 > qw) {  // wave-uniform: diagonal tile, needs mask
#pragma unroll
        for (int st = 0; st < 4; ++st)
#pragma unroll
          for (int r = 0; r < 4; ++r) {
            float v = sc[st][r] * SCL;
            if (s0 + st * 16 + l15 > qw + lg * 4 + r) v = -1e30f;
            sc[st][r] = v;
            tmax[r] = fmaxf(tmax[r], v);
          }
      } else {
#pragma unroll
        for (int st = 0; st < 4; ++st)
#pragma unroll
          for (int r = 0; r < 4; ++r) {
            const float v = sc[st][r] * SCL;
            sc[st][r] = v;
            tmax[r] = fmaxf(tmax[r], v);
          }
      }
#pragma unroll
      for (int r = 0; r < 4; ++r) {
        tmax[r] = fmaxf(tmax[r], __shfl_xor(tmax[r], 1));
        tmax[r] = fmaxf(tmax[r], __shfl_xor(tmax[r], 2));
        tmax[r] = fmaxf(tmax[r], __shfl_xor(tmax[r], 4));
        tmax[r] = fmaxf(tmax[r], __shfl_xor(tmax[r], 8));
      }
      float corr[4], psum[4];
#pragma unroll
      for (int r = 0; r < 4; ++r) {
        const float mn = fmaxf(mrun[r], tmax[r]);
        corr[r] = exp2f(mrun[r] - mn);
        mrun[r] = mn;
        psum[r] = 0.f;
      }
#pragma unroll
      for (int st = 0; st < 4; ++st)
#pragma unroll
        for (int r = 0; r < 4; ++r) {
          const float p = exp2f(sc[st][r] - mrun[r]);
          psum[r] += p;
          const int q = lg * 4 + r;
          Pw[q * 64 + SWZ(q, st * 16 + l15)] = f2bf(p);  // C-frag -> [q][s]
        }
#pragma unroll
      for (int r = 0; r < 4; ++r) {
        psum[r] += __shfl_xor(psum[r], 1);
        psum[r] += __shfl_xor(psum[r], 2);
        psum[r] += __shfl_xor(psum[r], 4);
        psum[r] += __shfl_xor(psum[r], 8);
        lrun[r] = lrun[r] * corr[r] + psum[r];
      }
#pragma unroll
      for (int dt = 0; dt < 4; ++dt)
#pragma unroll
        for (int r = 0; r < 4; ++r) o[dt][r] *= corr[r];
      // PV: O[16q][64d] += P[16q][64s] * V[64s][64d]
#pragma unroll
      for (int sc2 = 0; sc2 < 2; ++sc2) {
        const short8 pf =
            *reinterpret_cast<const short8*>(Pw + l15 * 64 + SWZ(l15, sc2 * 32 + lg * 8));
#pragma unroll
        for (int dt = 0; dt < 4; ++dt) {
          const int vr = dt * 16 + l15;
          const short8 vf =
              *reinterpret_cast<const short8*>(Vc + vr * 64 + SWZ(vr, sc2 * 32 + lg * 8));
          o[dt] = __builtin_amdgcn_mfma_f32_16x16x32_bf16(pf, vf, o[dt], 0, 0, 0);
        }
      }
      __syncthreads();  // implicit vmcnt(0): next tile staged AND buf[cur] free
      cur ^= 1;
    }
#pragma unroll
    for (int dt = 0; dt < 4; ++dt)
#pragma unroll
      for (int r = 0; r < 4; ++r) {
        const int t = qw + lg * 4 + r;
        const float val = o[dt][r] / lrun[r];
        ctx[(size_t)(b * 2048 + t) * 1024 + h * 64 + dt * 16 + l15] = f2bf(val);
      }
  }
}

// ---------------- launch ----------------------------------------------------
extern "C" void kernel_launch(void* const* d_in, const int* in_sizes, int n_in,
                              void* d_out, int out_size, void* d_ws, size_t ws_size,
                              hipStream_t stream) {
  const float* x = (const float*)d_in[0];
  const float* w_qkv = (const float*)d_in[1];
  const float* w_out = (const float*)d_in[2];
  // cache_k/cache_v/start_pos unused: start_pos=0, cache starts zero and is not returned.
  char* ws = (char*)d_ws;
  unsigned short* xb    = (unsigned short*)(ws);                       // 8 MiB
  unsigned short* wqkvb = (unsigned short*)(ws + (8ull  << 20));       // 6 MiB
  unsigned short* woutb = (unsigned short*)(ws + (14ull << 20));       // 2 MiB
  unsigned short* qkvb  = (unsigned short*)(ws + (16ull << 20));       // 24 MiB
  unsigned short* q_buf = (unsigned short*)(ws + (40ull << 20));       // 8 MiB
  unsigned short* k_buf = (unsigned short*)(ws + (48ull << 20));       // 8 MiB
  unsigned short* vt    = (unsigned short*)(ws + (56ull << 20));       // 8 MiB
  unsigned short* ctxb  = (unsigned short*)(ws + (64ull << 20));       // 8 MiB (total 72)

  cast_f32_bf16<<<4096, 256, 0, stream>>>(x, xb, 4194304 / 4);
  cast_f32_bf16<<<3072, 256, 0, stream>>>(w_qkv, wqkvb, 3145728 / 4);
  cast_f32_bf16<<<1024, 256, 0, stream>>>(w_out, woutb, 1048576 / 4);
  gemm_nt<1><<<dim3(32, 24), 256, 0, stream>>>(xb, wqkvb, qkvb, 4096, 3072, 1024);
  rope_qk<<<16384, 256, 0, stream>>>(qkvb, q_buf, k_buf);
  v_transpose<<<dim3(32, 32), 256, 0, stream>>>(qkvb, vt);
  attn_kernel<<<dim3(16, 32), 256, 0, stream>>>(q_buf, k_buf, vt, ctxb);
  gemm_nt<0><<<dim3(32, 8), 256, 0, stream>>>(ctxb, woutb, d_out, 4096, 1024, 1024);
}